// Round 1
// baseline (1156.878 us; speedup 1.0000x reference)
//
#include <hip/hip_runtime.h>
#include <hip/hip_bf16.h>

#define NN 512
#define SSAMP 64
#define NSTEP 400

// ---------- helpers ----------
__device__ __forceinline__ float wsum(float v){
  v += __shfl_xor(v, 32, 64);
  v += __shfl_xor(v, 16, 64);
  v += __shfl_xor(v,  8, 64);
  v += __shfl_xor(v,  4, 64);
  v += __shfl_xor(v,  2, 64);
  v += __shfl_xor(v,  1, 64);
  return v;
}
__device__ __forceinline__ float tanh_pos(float u){ // u >= 0
  float e = __expf(2.0f*u);
  return 1.0f - 2.0f/(e+1.0f);
}
__device__ __forceinline__ float tanh_gen(float u){
  float a = fabsf(u);
  float e = __expf(2.0f*a);
  float t = 1.0f - 2.0f/(e+1.0f);
  return copysignf(t, u);
}
__device__ __forceinline__ float h_tf(float a, float b, float d, float z){
  float x = fmaf(a, z, -b);
  float num = 1e-5f + fabsf(x);
  float den = 1e-5f*d + fabsf(1.0f - __expf(-d*x));
  return num/den;
}

__device__ __forceinline__ float l0_load(const float* p){ return *p; }
__device__ __forceinline__ float l0_load(const __hip_bfloat16* p){ return __bfloat162float(*p); }
__device__ __forceinline__ void  l0_store(float* p, float v){ *p = v; }
__device__ __forceinline__ void  l0_store(__hip_bfloat16* p, float v){ *p = __float2bfloat16(v); }

#define F4ELEM(v,m) ((m)==0?(v).x:(m)==1?(v).y:(m)==2?(v).z:(v).w)

// ---------- phase 1: w = 0.5*(exp(gc)*sc + (exp(gc)*sc)^T), normsq ----------
__global__ __launch_bounds__(256) void prep_w_kernel(
    const float* __restrict__ sc, const float* __restrict__ gc,
    float* __restrict__ w, float* __restrict__ normsq){
  int idx = blockIdx.x*256 + threadIdx.x;
  int i = idx >> 9, j = idx & 511;
  float a = __expf(gc[idx])*sc[idx];
  float b = __expf(gc[j*NN+i])*sc[j*NN+i];
  float wij = 0.5f*(a + b);
  w[idx] = wij;
  float p = wsum(wij*wij);
  if ((threadIdx.x & 63) == 0) atomicAdd(normsq, p);
}

// ---------- phase 1b: lap = (w - diag(rowsum(w))) / norm ----------
__global__ __launch_bounds__(64) void prep_lap_kernel(
    const float* __restrict__ w, const float* __restrict__ normsq,
    float* __restrict__ lap){
  int i = blockIdx.x;
  int l = threadIdx.x; // 0..63
  float vals[8]; float s = 0.f;
  #pragma unroll
  for (int j=0;j<8;j++){ vals[j] = w[i*NN + j*64 + l]; s += vals[j]; }
  float rs = wsum(s);
  float rn = 1.0f/sqrtf(normsq[0]);
  #pragma unroll
  for (int j=0;j<8;j++){
    int col = j*64 + l;
    float x = vals[j] - (col==i ? rs : 0.0f);
    lap[i*NN+col] = x*rn;
  }
}

// ---------- phase 2: L0[t] = lap @ e0[t]  (400 batches, fp32) ----------
template<typename TL>
__global__ __launch_bounds__(256) void gemm_kernel(
    const float* __restrict__ lap, const float* __restrict__ nE0,
    TL* __restrict__ L0){
  __shared__ __align__(16) float e0s[64][64];
  int t = blockIdx.y;
  int tid = threadIdx.x;
  int ts = tid & 7, tr = tid >> 3;
  int r0 = blockIdx.x*128 + tr*4;
  int s0 = ts*8;
  const float* e0t = nE0 + (size_t)t*NN*SSAMP;
  float acc[4][8];
  #pragma unroll
  for (int i=0;i<4;i++)
    #pragma unroll
    for (int j=0;j<8;j++) acc[i][j]=0.f;

  for (int kt=0; kt<8; ++kt){
    int kr = tid>>4, c4 = (tid&15)*4;
    const float* src = e0t + (size_t)(kt*64+kr)*SSAMP + c4;
    float4 a0 = *(const float4*)(src);
    float4 a1 = *(const float4*)(src + 16*SSAMP);
    float4 a2 = *(const float4*)(src + 32*SSAMP);
    float4 a3 = *(const float4*)(src + 48*SSAMP);
    __syncthreads();             // prior-tile reads done before overwrite
    *(float4*)(&e0s[kr   ][c4]) = a0;
    *(float4*)(&e0s[kr+16][c4]) = a1;
    *(float4*)(&e0s[kr+32][c4]) = a2;
    *(float4*)(&e0s[kr+48][c4]) = a3;
    __syncthreads();
    const float* lb = lap + (size_t)r0*NN + kt*64;
    for (int kk=0; kk<64; kk+=4){
      float4 lq0 = *(const float4*)(lb +        kk);
      float4 lq1 = *(const float4*)(lb +   NN + kk);
      float4 lq2 = *(const float4*)(lb + 2*NN + kk);
      float4 lq3 = *(const float4*)(lb + 3*NN + kk);
      #pragma unroll
      for (int m=0;m<4;m++){
        float lm[4] = {F4ELEM(lq0,m), F4ELEM(lq1,m), F4ELEM(lq2,m), F4ELEM(lq3,m)};
        float4 ea = *(const float4*)(&e0s[kk+m][s0]);
        float4 eb = *(const float4*)(&e0s[kk+m][s0+4]);
        float ev[8] = {ea.x,ea.y,ea.z,ea.w, eb.x,eb.y,eb.z,eb.w};
        #pragma unroll
        for (int i=0;i<4;i++)
          #pragma unroll
          for (int j=0;j<8;j++)
            acc[i][j] = fmaf(lm[i], ev[j], acc[i][j]);
      }
    }
  }
  #pragma unroll
  for (int i=0;i<4;i++){
    TL* dst = L0 + ((size_t)t*NN + r0 + i)*SSAMP + s0;
    #pragma unroll
    for (int j=0;j<8;j++) l0_store(&dst[j], acc[i][j]);
  }
}

// ---------- phase 3: sequential 400-step dynamics ----------
// 128 blocks x 256 threads; block owns 4 nodes (one wave each), lane = sample.
// Cross-block exchange: packed (tag<<32 | f32bits(hxE)) 64-bit agent atomics,
// double-buffered by step parity. No fences needed: tag+value share one word,
// and the published value is data-dependent on all polled loads.
template<typename TL>
__global__ __launch_bounds__(256) void seq_kernel(
    const float* __restrict__ external, const float* __restrict__ hx,
    const float* __restrict__ lap, const TL* __restrict__ L0,
    const float* __restrict__ nE0, const float* __restrict__ nI0,
    const float* __restrict__ nE,  const float* __restrict__ nI,
    const float* __restrict__ nB,
    const float* __restrict__ gp,   const float* __restrict__ gEEp,
    const float* __restrict__ gIEp, const float* __restrict__ gEIp,
    const float* __restrict__ stdinp, const float* __restrict__ stdoutp,
    unsigned long long* __restrict__ xbuf,  // 2*512 packed words
    float* __restrict__ out)
{
  __shared__ float hxs[NN];
  const int tid  = threadIdx.x;
  const int wv   = tid >> 6, lane = tid & 63;
  const int n    = blockIdx.x*4 + wv;

  const float g    = gp[0];
  const float gEE  = 0.001f + fmaxf(gEEp[0], 0.f);
  const float gIE  = 0.001f + fmaxf(gIEp[0], 0.f);
  const float gEI  = 0.001f + fmaxf(gEIp[0], 0.f);
  const float sdin = 0.02f  + fmaxf(stdinp[0], 0.f);
  const float sdout=          fmaxf(stdoutp[0], 0.f);
  const float sqin = 0.22360679774997896f * sdin;  // sqrt(DT)*std_in_e

  float hxE = hx[n*6+0], hxI = hx[n*6+1];
  float xs  = hx[n*6+2], fs  = hx[n*6+3], vs = hx[n*6+4], qs = hx[n*6+5];

  // publish version 0 (tag = 1)
  if (lane==0){
    unsigned long long pk = (1ULL<<32) | (unsigned long long)__float_as_uint(hxE);
    __hip_atomic_store(&xbuf[n], pk, __ATOMIC_RELAXED, __HIP_MEMORY_SCOPE_AGENT);
  }

  const size_t nsbase = (size_t)n*SSAMP + lane;
  float c_e0 = nE0[nsbase];
  float c_i0 = nI0[nsbase];
  float c_eE = nE [nsbase];
  float c_eI = nI [nsbase];
  float c_L0 = l0_load(&L0[nsbase]);
  float c_ex = external[n*400 + 0];

  const float* laprow = lap + (size_t)n*NN;

  #pragma unroll 1
  for (int t=0; t<NSTEP; ++t){
    // prefetch next step's per-thread data (1-step distance)
    int tn = (t+1 < NSTEP) ? t+1 : t;
    size_t offn = (size_t)tn*NN*SSAMP + nsbase;
    float p_e0 = nE0[offn], p_i0 = nI0[offn], p_eE = nE[offn], p_eI = nI[offn];
    float p_L0 = l0_load(&L0[offn]);
    float p_ex = external[n*400 + (tn%20)*20 + (tn/20)];

    // ---- local (exchange-independent) part ----
    float E = fmaf(0.02f , c_e0, hxE);
    float I = fmaf(0.001f, c_i0, hxI);
    float II = tanh_pos(fmaxf(fmaf(gEI, E, 0.224f) - I, 0.f));   // W_I*I_0 = 0.224
    float rI = h_tf(615.0f, 177.0f, 0.087f, II);
    float In = I + 0.05f*fmaf(-100.0f, I, rI) + sqin*c_eI;       // GAMMA_I=1, 1/TAU_I=100
    float Ip = tanh_pos(fmaxf(In, 0.f));
    float Im = fmaxf(wsum(Ip)*0.015625f, 1e-5f);
    float IEpre = 0.32f + 0.02f*c_ex + gEE*E + g*0.02f*c_L0 - gIE*I;

    // ---- exchange: wait for all nodes' hxE of version t ----
    const unsigned long long want = (unsigned long long)(t+1);
    unsigned long long* bc = xbuf + (size_t)(t&1)*NN;
    unsigned long long u0, u1;
    for(;;){
      u0 = __hip_atomic_load(&bc[tid],     __ATOMIC_RELAXED, __HIP_MEMORY_SCOPE_AGENT);
      u1 = __hip_atomic_load(&bc[tid+256], __ATOMIC_RELAXED, __HIP_MEMORY_SCOPE_AGENT);
      int ok = (int)(((u0>>32)==want) & ((u1>>32)==want));
      if (__syncthreads_and(ok)) break;
    }
    hxs[tid]     = __uint_as_float((unsigned int)u0);
    hxs[tid+256] = __uint_as_float((unsigned int)u1);
    __syncthreads();

    // ---- matvec row: lapHx[n] = sum_k lap[n,k]*hxE[k] ----
    float mv = 0.f;
    #pragma unroll
    for (int j=0;j<8;j++) mv = fmaf(laprow[j*64+lane], hxs[j*64+lane], mv);
    float lapHx = wsum(mv);

    float IE = tanh_pos(fmaxf(fmaf(g, lapHx, IEpre), 0.f));
    float rE = h_tf(310.0f, 125.0f, 0.16f, IE);
    float En = E + 0.05f*fmaf(0.641f*(1.0f-E), rE, -10.0f*E) + sqin*c_eE;
    float Ep = tanh_pos(fmaxf(En, 0.f));
    float Em = fmaxf(wsum(Ep)*0.015625f, 1e-5f);

    // ---- publish version t+1 ASAP (critical path) ----
    if (lane==0){
      unsigned long long pk = ((unsigned long long)(t+2)<<32)
                            | (unsigned long long)__float_as_uint(Em);
      __hip_atomic_store(&xbuf[(size_t)((t+1)&1)*NN + n], pk,
                         __ATOMIC_RELAXED, __HIP_MEMORY_SCOPE_AGENT);
    }

    // ---- hemodynamics (per node; redundantly on all lanes) ----
    float va = __expf(3.125f*__logf(vs));                        // v^(1/ALPHA)
    float xn = xs + 0.05f*(Em - xs*1.5384615384615385f - (fs-1.0f)*2.4390243902439024f);
    float fn = fs + 0.05f*xs;
    float vn = vs + 0.05f*(fs - va)*1.0204081632653061f;
    float qn = qs + 0.05f*( fs*(1.0f - __expf(-0.41551544396166582f/fs))*2.9411764705882355f
                            - qs*va/vs )*1.0204081632653061f;
    xs = tanh_gen(xn);
    fs = 1.0f + tanh_gen(fn - 1.0f);
    vs = 1.0f + tanh_gen(vn - 1.0f);
    qs = 1.0f + tanh_gen(qn - 1.0f);
    hxE = Em; hxI = Im;

    // ---- BOLD readout at TR boundary ----
    if (((t+1) % 20) == 0 && lane==0){
      int tr = t/20;
      float eb = nB[tr*NN + n];
      float bold = sdout*eb + 5.882352941176471f*( 2.38f*(1.0f-qs)
                   + 2.0f*(1.0f - qs/vs) + 0.48f*(1.0f-vs) );
      out[n*20 + tr] = bold;
    }

    c_e0=p_e0; c_i0=p_i0; c_eE=p_eE; c_eI=p_eI; c_L0=p_L0; c_ex=p_ex;
  }
}

// ---------- host ----------
extern "C" void kernel_launch(void* const* d_in, const int* in_sizes, int n_in,
                              void* d_out, int out_size, void* d_ws, size_t ws_size,
                              hipStream_t stream) {
  (void)in_sizes; (void)n_in; (void)out_size;
  const float* external = (const float*)d_in[0];
  const float* hx   = (const float*)d_in[1];
  // d_in[2] = hE (unused by reference)
  const float* sc   = (const float*)d_in[3];
  const float* gc   = (const float*)d_in[4];
  const float* gp   = (const float*)d_in[5];
  const float* gEE  = (const float*)d_in[6];
  const float* gIE  = (const float*)d_in[7];
  const float* gEI  = (const float*)d_in[8];
  const float* stdi = (const float*)d_in[9];
  const float* stdo = (const float*)d_in[10];
  const float* nE0  = (const float*)d_in[11];
  const float* nI0  = (const float*)d_in[12];
  const float* nE   = (const float*)d_in[13];
  const float* nI   = (const float*)d_in[14];
  const float* nB   = (const float*)d_in[15];
  float* out = (float*)d_out;

  char* ws = (char*)d_ws;
  float* normsq = (float*)ws;                                   // 4 B @ 0
  unsigned long long* xbuf = (unsigned long long*)(ws + 256);   // 2*512*8 B
  float* w   = (float*)(ws + 16384);                            // 1 MB
  float* lap = (float*)(ws + 16384 + (1<<20));                  // 1 MB
  char*  l0p = ws + 16384 + (2<<20);                            // L0

  hipMemsetAsync(ws, 0, 16384, stream);
  prep_w_kernel  <<<1024, 256, 0, stream>>>(sc, gc, w, normsq);
  prep_lap_kernel<<< 512,  64, 0, stream>>>(w, normsq, lap);

  size_t l0_f32  = (size_t)NSTEP*NN*SSAMP*sizeof(float);
  size_t need_f32 = 16384 + (2<<20) + l0_f32;
  if (ws_size >= need_f32){
    gemm_kernel<float><<<dim3(4,NSTEP), 256, 0, stream>>>(lap, nE0, (float*)l0p);
    seq_kernel<float><<<128, 256, 0, stream>>>(external, hx, lap, (const float*)l0p,
        nE0, nI0, nE, nI, nB, gp, gEE, gIE, gEI, stdi, stdo, xbuf, out);
  } else {
    gemm_kernel<__hip_bfloat16><<<dim3(4,NSTEP), 256, 0, stream>>>(lap, nE0, (__hip_bfloat16*)l0p);
    seq_kernel<__hip_bfloat16><<<128, 256, 0, stream>>>(external, hx, lap, (const __hip_bfloat16*)l0p,
        nE0, nI0, nE, nI, nB, gp, gEE, gIE, gEI, stdi, stdo, xbuf, out);
  }
}

// Round 2
// 1152.231 us; speedup vs baseline: 1.0040x; 1.0040x over previous
//
#include <hip/hip_runtime.h>
#include <hip/hip_bf16.h>

#define NN 512
#define SSAMP 64
#define NSTEP 400

typedef __attribute__((ext_vector_type(4))) float f32x4;
typedef __attribute__((ext_vector_type(8))) short s16x8;

// ---------- helpers ----------
__device__ __forceinline__ float wsum(float v){
  v += __shfl_xor(v, 32, 64);
  v += __shfl_xor(v, 16, 64);
  v += __shfl_xor(v,  8, 64);
  v += __shfl_xor(v,  4, 64);
  v += __shfl_xor(v,  2, 64);
  v += __shfl_xor(v,  1, 64);
  return v;
}
__device__ __forceinline__ float tanh_pos(float u){ // u >= 0
  float e = __expf(2.0f*u);
  return 1.0f - 2.0f/(e+1.0f);
}
__device__ __forceinline__ float tanh_gen(float u){
  float a = fabsf(u);
  float e = __expf(2.0f*a);
  float t = 1.0f - 2.0f/(e+1.0f);
  return copysignf(t, u);
}
__device__ __forceinline__ float h_tf(float a, float b, float d, float z){
  float x = fmaf(a, z, -b);
  float num = 1e-5f + fabsf(x);
  float den = 1e-5f*d + fabsf(1.0f - __expf(-d*x));
  return num/den;
}
// pack positive fp32 into 24 bits (round) + 8-bit tag
__device__ __forceinline__ unsigned pack24(float v, unsigned tag){
  unsigned fb = __float_as_uint(v);
  return (tag<<24) | ((fb + 0x80u) >> 8);
}
__device__ __forceinline__ float unpack24(unsigned u){
  return __uint_as_float(u << 8);
}

#define F4ELEM(v,m) ((m)==0?(v).x:(m)==1?(v).y:(m)==2?(v).z:(v).w)

// ---------- phase 1: w = 0.5*(exp(gc)*sc + (exp(gc)*sc)^T), normsq ----------
__global__ __launch_bounds__(256) void prep_w_kernel(
    const float* __restrict__ sc, const float* __restrict__ gc,
    float* __restrict__ w, float* __restrict__ normsq){
  int idx = blockIdx.x*256 + threadIdx.x;
  int i = idx >> 9, j = idx & 511;
  float a = __expf(gc[idx])*sc[idx];
  float b = __expf(gc[j*NN+i])*sc[j*NN+i];
  float wij = 0.5f*(a + b);
  w[idx] = wij;
  float p = wsum(wij*wij);
  if ((threadIdx.x & 63) == 0) atomicAdd(normsq, p);
}

// ---------- phase 1b: lap = (w - diag(rowsum(w))) / norm ----------
__global__ __launch_bounds__(64) void prep_lap_kernel(
    const float* __restrict__ w, const float* __restrict__ normsq,
    float* __restrict__ lap){
  int i = blockIdx.x;
  int l = threadIdx.x; // 0..63
  float vals[8]; float s = 0.f;
  #pragma unroll
  for (int j=0;j<8;j++){ vals[j] = w[i*NN + j*64 + l]; s += vals[j]; }
  float rs = wsum(s);
  float rn = 1.0f/sqrtf(normsq[0]);
  #pragma unroll
  for (int j=0;j<8;j++){
    int col = j*64 + l;
    float x = vals[j] - (col==i ? rs : 0.0f);
    lap[i*NN+col] = x*rn;
  }
}

// ---------- phase 1c: split lap into bf16 hi/lo ----------
__global__ __launch_bounds__(256) void lap_split_kernel(
    const float* __restrict__ lap,
    __hip_bfloat16* __restrict__ lh, __hip_bfloat16* __restrict__ ll){
  int i = blockIdx.x*256 + threadIdx.x;
  float f = lap[i];
  __hip_bfloat16 h = __float2bfloat16(f);
  lh[i] = h;
  ll[i] = __float2bfloat16(f - __bfloat162float(h));
}

// ---------- phase 2a: transpose+split e0: [t][n][s] f32 -> [t][s][n] bf16 hi/lo
__global__ __launch_bounds__(256) void e0t_kernel(
    const float* __restrict__ nE0,
    __hip_bfloat16* __restrict__ th, __hip_bfloat16* __restrict__ tl){
  __shared__ float tile[64][65];
  int t = blockIdx.y, c = blockIdx.x;              // c: node chunk (8 x 64)
  const float* src = nE0 + ((size_t)t*NN + c*64)*SSAMP;
  int tid = threadIdx.x;
  int r0 = tid>>2, c4 = (tid&3)*16;
  #pragma unroll
  for (int i=0;i<4;i++){
    float4 v = *(const float4*)(src + r0*64 + c4 + i*4);
    tile[r0][c4+i*4+0]=v.x; tile[r0][c4+i*4+1]=v.y;
    tile[r0][c4+i*4+2]=v.z; tile[r0][c4+i*4+3]=v.w;
  }
  __syncthreads();
  int s = tid>>2, nseg = (tid&3)*16;
  __hip_bfloat16 hs[16], ls[16];
  #pragma unroll
  for (int i=0;i<16;i++){
    float f = tile[nseg+i][s];
    __hip_bfloat16 h = __float2bfloat16(f);
    hs[i] = h;
    ls[i] = __float2bfloat16(f - __bfloat162float(h));
  }
  size_t doff = ((size_t)t*64 + s)*NN + c*64 + nseg;
  *(uint4*)(th + doff)     = *(uint4*)&hs[0];
  *(uint4*)(th + doff + 8) = *(uint4*)&hs[8];
  *(uint4*)(tl + doff)     = *(uint4*)&ls[0];
  *(uint4*)(tl + doff + 8) = *(uint4*)&ls[8];
}

// ---------- phase 2b: L0[t][n][s] = lap @ e0[t]  via MFMA, split-bf16 ----------
// C^T orientation: D = A(e0T, M=64 x K=512) * B(lap, K=512 x N=512); lap symmetric.
__global__ __launch_bounds__(256) void mfma_gemm_kernel(
    const __hip_bfloat16* __restrict__ Ah, const __hip_bfloat16* __restrict__ Al,
    const __hip_bfloat16* __restrict__ Bh, const __hip_bfloat16* __restrict__ Bl,
    float* __restrict__ L0){
  int t = blockIdx.y;
  int nb = blockIdx.x;                       // 0..3, 128 cols each
  int w  = threadIdx.x>>6, l = threadIdx.x&63;
  int lr = l&15, lg = l>>4;                  // tile row/col, k-group
  f32x4 acc[4][2] = {};
  const short* ahp = (const short*)Ah + ((size_t)t*64 + lr)*NN + lg*8;
  const short* alp = (const short*)Al + ((size_t)t*64 + lr)*NN + lg*8;
  int col0 = nb*128 + w*32 + lr;
  const short* bhp = (const short*)Bh + (size_t)col0*NN + lg*8;
  const short* blp = (const short*)Bl + (size_t)col0*NN + lg*8;
  for (int k0=0; k0<NN; k0+=32){
    s16x8 a_h[4], a_l[4], b_h[2], b_l[2];
    #pragma unroll
    for (int mt=0;mt<4;mt++){
      a_h[mt] = *(const s16x8*)(ahp + mt*16*NN + k0);
      a_l[mt] = *(const s16x8*)(alp + mt*16*NN + k0);
    }
    #pragma unroll
    for (int nt=0;nt<2;nt++){
      b_h[nt] = *(const s16x8*)(bhp + nt*16*NN + k0);
      b_l[nt] = *(const s16x8*)(blp + nt*16*NN + k0);
    }
    #pragma unroll
    for (int mt=0;mt<4;mt++)
      #pragma unroll
      for (int nt=0;nt<2;nt++){
        acc[mt][nt] = __builtin_amdgcn_mfma_f32_16x16x32_bf16(a_h[mt], b_h[nt], acc[mt][nt],0,0,0);
        acc[mt][nt] = __builtin_amdgcn_mfma_f32_16x16x32_bf16(a_l[mt], b_h[nt], acc[mt][nt],0,0,0);
        acc[mt][nt] = __builtin_amdgcn_mfma_f32_16x16x32_bf16(a_h[mt], b_l[nt], acc[mt][nt],0,0,0);
      }
  }
  // D[m=s][n=col]: lane holds col=lr, rows lg*4+reg (4 contiguous s)
  #pragma unroll
  for (int mt=0;mt<4;mt++)
    #pragma unroll
    for (int nt=0;nt<2;nt++){
      float* dst = L0 + ((size_t)t*NN + nb*128 + w*32 + nt*16 + lr)*SSAMP + mt*16 + lg*4;
      *(f32x4*)dst = acc[mt][nt];
    }
}

// ---------- phase 2 fallback: fp32 VALU gemm (round-0) ----------
__global__ __launch_bounds__(256) void gemm_fallback_kernel(
    const float* __restrict__ lap, const float* __restrict__ nE0,
    float* __restrict__ L0){
  __shared__ __align__(16) float e0s[64][64];
  int t = blockIdx.y;
  int tid = threadIdx.x;
  int ts = tid & 7, tr = tid >> 3;
  int r0 = blockIdx.x*128 + tr*4;
  int s0 = ts*8;
  const float* e0t = nE0 + (size_t)t*NN*SSAMP;
  float acc[4][8];
  #pragma unroll
  for (int i=0;i<4;i++)
    #pragma unroll
    for (int j=0;j<8;j++) acc[i][j]=0.f;
  for (int kt=0; kt<8; ++kt){
    int kr = tid>>4, c4 = (tid&15)*4;
    const float* src = e0t + (size_t)(kt*64+kr)*SSAMP + c4;
    float4 a0 = *(const float4*)(src);
    float4 a1 = *(const float4*)(src + 16*SSAMP);
    float4 a2 = *(const float4*)(src + 32*SSAMP);
    float4 a3 = *(const float4*)(src + 48*SSAMP);
    __syncthreads();
    *(float4*)(&e0s[kr   ][c4]) = a0;
    *(float4*)(&e0s[kr+16][c4]) = a1;
    *(float4*)(&e0s[kr+32][c4]) = a2;
    *(float4*)(&e0s[kr+48][c4]) = a3;
    __syncthreads();
    const float* lb = lap + (size_t)r0*NN + kt*64;
    for (int kk=0; kk<64; kk+=4){
      float4 lq0 = *(const float4*)(lb +        kk);
      float4 lq1 = *(const float4*)(lb +   NN + kk);
      float4 lq2 = *(const float4*)(lb + 2*NN + kk);
      float4 lq3 = *(const float4*)(lb + 3*NN + kk);
      #pragma unroll
      for (int m=0;m<4;m++){
        float lm[4] = {F4ELEM(lq0,m), F4ELEM(lq1,m), F4ELEM(lq2,m), F4ELEM(lq3,m)};
        float4 ea = *(const float4*)(&e0s[kk+m][s0]);
        float4 eb = *(const float4*)(&e0s[kk+m][s0+4]);
        float ev[8] = {ea.x,ea.y,ea.z,ea.w, eb.x,eb.y,eb.z,eb.w};
        #pragma unroll
        for (int i=0;i<4;i++)
          #pragma unroll
          for (int j=0;j<8;j++)
            acc[i][j] = fmaf(lm[i], ev[j], acc[i][j]);
      }
    }
  }
  #pragma unroll
  for (int i=0;i<4;i++){
    float* dst = L0 + ((size_t)t*NN + r0 + i)*SSAMP + s0;
    #pragma unroll
    for (int j=0;j<8;j++) dst[j] = acc[i][j];
  }
}

// ---------- phase 3: sequential 400-step dynamics ----------
// 128 blocks x 256 threads; waves fully independent (no barriers, no LDS).
// Wave owns node n; lane = sample. lap row lives in 8 registers.
// Exchange: 4B packed (tag8 | f24) agent atomics, double-buffered by parity.
__global__ __launch_bounds__(256) void seq_kernel(
    const float* __restrict__ external, const float* __restrict__ hx,
    const float* __restrict__ lap, const float* __restrict__ L0,
    const float* __restrict__ nE0, const float* __restrict__ nI0,
    const float* __restrict__ nE,  const float* __restrict__ nI,
    const float* __restrict__ nB,
    const float* __restrict__ gp,   const float* __restrict__ gEEp,
    const float* __restrict__ gIEp, const float* __restrict__ gEIp,
    const float* __restrict__ stdinp, const float* __restrict__ stdoutp,
    unsigned* __restrict__ xbuf,  // 2*512 packed words
    float* __restrict__ out)
{
  const int tid  = threadIdx.x;
  const int wv   = tid >> 6, lane = tid & 63;
  const int n    = blockIdx.x*4 + wv;

  const float g    = gp[0];
  const float gEE  = 0.001f + fmaxf(gEEp[0], 0.f);
  const float gIE  = 0.001f + fmaxf(gIEp[0], 0.f);
  const float gEI  = 0.001f + fmaxf(gEIp[0], 0.f);
  const float sdin = 0.02f  + fmaxf(stdinp[0], 0.f);
  const float sdout=          fmaxf(stdoutp[0], 0.f);
  const float sqin = 0.22360679774997896f * sdin;

  float hxE = hx[n*6+0], hxI = hx[n*6+1];
  float xs  = hx[n*6+2], fs  = hx[n*6+3], vs = hx[n*6+4], qs = hx[n*6+5];

  // lap row in registers for the whole kernel
  float lr[8];
  #pragma unroll
  for (int j=0;j<8;j++) lr[j] = lap[(size_t)n*NN + j*64 + lane];

  // publish version 0 (tag=1) into bank 0
  if (lane==0)
    __hip_atomic_store(&xbuf[n], pack24(hxE, 1u),
                       __ATOMIC_RELAXED, __HIP_MEMORY_SCOPE_AGENT);

  const size_t nsbase = (size_t)n*SSAMP + lane;
  float c_e0 = nE0[nsbase];
  float c_i0 = nI0[nsbase];
  float c_eE = nE [nsbase];
  float c_eI = nI [nsbase];
  float c_L0 = L0 [nsbase];
  float c_ex = external[n*400 + 0];

  #pragma unroll 1
  for (int t=0; t<NSTEP; ++t){
    // prefetch next step's per-thread data
    int tn = (t+1 < NSTEP) ? t+1 : t;
    size_t offn = (size_t)tn*NN*SSAMP + nsbase;
    float p_e0 = nE0[offn], p_i0 = nI0[offn], p_eE = nE[offn], p_eI = nI[offn];
    float p_L0 = L0[offn];
    float p_ex = external[n*400 + (tn%20)*20 + (tn/20)];

    // ---- exchange-independent work (overlaps others' publish latency) ----
    float E = fmaf(0.02f , c_e0, hxE);
    float I = fmaf(0.001f, c_i0, hxI);
    float II = tanh_pos(fmaxf(fmaf(gEI, E, 0.224f) - I, 0.f));
    float rI = h_tf(615.0f, 177.0f, 0.087f, II);
    float In = I + 0.05f*fmaf(-100.0f, I, rI) + sqin*c_eI;
    float Ip = tanh_pos(fmaxf(In, 0.f));
    float Im = fmaxf(wsum(Ip)*0.015625f, 1e-5f);
    float IEpre = 0.32f + 0.02f*c_ex + gEE*E + g*0.02f*c_L0 - gIE*I;

    // ---- poll: lane j-words of bank t&1 until all tagged t+1 ----
    const unsigned want = (unsigned)(t+1) & 0xFFu;
    unsigned* bc = xbuf + (size_t)(t&1)*NN;
    unsigned u[8];
    for(;;){
      #pragma unroll
      for (int j=0;j<8;j++)
        u[j] = __hip_atomic_load(&bc[j*64+lane], __ATOMIC_RELAXED, __HIP_MEMORY_SCOPE_AGENT);
      int ok = 1;
      #pragma unroll
      for (int j=0;j<8;j++) ok &= (int)((u[j]>>24) == want);
      if (__all(ok)) break;
    }

    // ---- matvec from registers ----
    float mv = 0.f;
    #pragma unroll
    for (int j=0;j<8;j++) mv = fmaf(lr[j], unpack24(u[j]), mv);
    float lapHx = wsum(mv);

    float IE = tanh_pos(fmaxf(fmaf(g, lapHx, IEpre), 0.f));
    float rE = h_tf(310.0f, 125.0f, 0.16f, IE);
    float En = E + 0.05f*fmaf(0.641f*(1.0f-E), rE, -10.0f*E) + sqin*c_eE;
    float Ep = tanh_pos(fmaxf(En, 0.f));
    float Em = fmaxf(wsum(Ep)*0.015625f, 1e-5f);

    // ---- publish version t+1 ASAP ----
    if (lane==0)
      __hip_atomic_store(&xbuf[(size_t)((t+1)&1)*NN + n],
                         pack24(Em, (unsigned)(t+2) & 0xFFu),
                         __ATOMIC_RELAXED, __HIP_MEMORY_SCOPE_AGENT);

    // ---- hemodynamics (off critical path) ----
    float va = __expf(3.125f*__logf(vs));
    float xn = xs + 0.05f*(Em - xs*1.5384615384615385f - (fs-1.0f)*2.4390243902439024f);
    float fn = fs + 0.05f*xs;
    float vn = vs + 0.05f*(fs - va)*1.0204081632653061f;
    float qn = qs + 0.05f*( fs*(1.0f - __expf(-0.41551544396166582f/fs))*2.9411764705882355f
                            - qs*va/vs )*1.0204081632653061f;
    xs = tanh_gen(xn);
    fs = 1.0f + tanh_gen(fn - 1.0f);
    vs = 1.0f + tanh_gen(vn - 1.0f);
    qs = 1.0f + tanh_gen(qn - 1.0f);
    hxE = Em; hxI = Im;

    if (((t+1) % 20) == 0 && lane==0){
      int tr = t/20;
      float eb = nB[tr*NN + n];
      float bold = sdout*eb + 5.882352941176471f*( 2.38f*(1.0f-qs)
                   + 2.0f*(1.0f - qs/vs) + 0.48f*(1.0f-vs) );
      out[n*20 + tr] = bold;
    }

    c_e0=p_e0; c_i0=p_i0; c_eE=p_eE; c_eI=p_eI; c_L0=p_L0; c_ex=p_ex;
  }
}

// ---------- host ----------
extern "C" void kernel_launch(void* const* d_in, const int* in_sizes, int n_in,
                              void* d_out, int out_size, void* d_ws, size_t ws_size,
                              hipStream_t stream) {
  (void)in_sizes; (void)n_in; (void)out_size;
  const float* external = (const float*)d_in[0];
  const float* hx   = (const float*)d_in[1];
  const float* sc   = (const float*)d_in[3];
  const float* gc   = (const float*)d_in[4];
  const float* gp   = (const float*)d_in[5];
  const float* gEE  = (const float*)d_in[6];
  const float* gIE  = (const float*)d_in[7];
  const float* gEI  = (const float*)d_in[8];
  const float* stdi = (const float*)d_in[9];
  const float* stdo = (const float*)d_in[10];
  const float* nE0  = (const float*)d_in[11];
  const float* nI0  = (const float*)d_in[12];
  const float* nE   = (const float*)d_in[13];
  const float* nI   = (const float*)d_in[14];
  const float* nB   = (const float*)d_in[15];
  float* out = (float*)d_out;

  char* ws = (char*)d_ws;
  const size_t MB = 1048576;
  float*    normsq = (float*)ws;                        // 4 B
  unsigned* xbuf   = (unsigned*)(ws + 256);             // 2*512*4 B
  float* w    = (float*)(ws + 8192);                    // 1 MB
  float* lap  = (float*)(ws + 8192 + 1*MB);             // 1 MB
  __hip_bfloat16* lh = (__hip_bfloat16*)(ws + 8192 + 2*MB);          // 512 KB
  __hip_bfloat16* ll = (__hip_bfloat16*)(ws + 8192 + 2*MB + 512*1024);
  float* L0 = (float*)(ws + 8192 + 3*MB);               // 52428800 B
  size_t l0b = (size_t)NSTEP*NN*SSAMP*sizeof(float);
  __hip_bfloat16* th = (__hip_bfloat16*)(ws + 8192 + 3*MB + l0b);    // 26214400 B
  __hip_bfloat16* tl = th + (size_t)NSTEP*64*NN;

  hipMemsetAsync(ws, 0, 8192, stream);
  prep_w_kernel  <<<1024, 256, 0, stream>>>(sc, gc, w, normsq);
  prep_lap_kernel<<< 512,  64, 0, stream>>>(w, normsq, lap);

  size_t need_full = 8192 + 3*MB + l0b + 2*(size_t)NSTEP*64*NN*sizeof(__hip_bfloat16);
  if (ws_size >= need_full){
    lap_split_kernel<<<1024, 256, 0, stream>>>(lap, lh, ll);
    e0t_kernel<<<dim3(8, NSTEP), 256, 0, stream>>>(nE0, th, tl);
    mfma_gemm_kernel<<<dim3(4, NSTEP), 256, 0, stream>>>(th, tl, lh, ll, L0);
  } else {
    gemm_fallback_kernel<<<dim3(4, NSTEP), 256, 0, stream>>>(lap, nE0, L0);
  }
  seq_kernel<<<128, 256, 0, stream>>>(external, hx, lap, L0,
      nE0, nI0, nE, nI, nB, gp, gEE, gIE, gEI, stdi, stdo, xbuf, out);
}